// Round 15
// baseline (115.452 us; speedup 1.0000x reference)
//
#include <hip/hip_runtime.h>
#include <math.h>

// Unfused mul/add everywhere: the np-exact chain (phase 3) requires separately
// rounded mul/add; phases 1-2 are unaffected semantically.
#pragma clang fp contract(off)

// MoE gate: logits = x @ W^T + bias ; softmax ; top-8 ; dense scatter.
// Outputs (float32): vals[16384*8] | idx[16384*8] | dense[16384*64].
//
// r15 = r14 with the grid bug fixed: finish_kernel covers 4 rows/block
// (4 waves, one row per wave) -> grid must be NROWS/4 = 4096 (r14 launched
// NROWS/64 = 256, leaving 15360 rows unwritten -> idx absmax 63).
//  P1 mfma_logits: split-bf16 3-pass MFMA GEMM -> approx logits (~2.5e-5 err).
//  P2 finish: one wave per row; shfl-reduce softmax; top-9 via lexicographic
//     tournament (== serial strict-> lowest-idx scan); ballot flagging of
//     near-tie rows (gap < 1e-4) into d_ws.
//  P3 exact_fix: bit-exact np chain (npyv SSE2/SSE3: reverse in-block order,
//     unfused mul/add, hadd tree) for flagged rows; re-rank; rewrite.

#define NROWS 16384
#define DIM   2048
#define NE    64
#define KSTEP 32
#define NKT   (DIM / KSTEP)   // 64
#define MARGIN 1e-4f
#define MAXCAND 12

typedef float f32x4 __attribute__((ext_vector_type(4)));
typedef short s16x8 __attribute__((ext_vector_type(8)));

__device__ __forceinline__ void ld16_lds(const float* g, void* l) {
  __builtin_amdgcn_global_load_lds((const __attribute__((address_space(1))) void*)g,
                                   (__attribute__((address_space(3))) void*)l, 16, 0, 0);
}
__device__ __forceinline__ unsigned short bf16_rne(float f) {
  unsigned u = __builtin_bit_cast(unsigned, f);
  u += 0x7FFFu + ((u >> 16) & 1u);
  return (unsigned short)(u >> 16);
}
__device__ __forceinline__ float bf16f(unsigned short h) {
  return __builtin_bit_cast(float, (unsigned)h << 16);
}
__device__ __forceinline__ void cvt8(const f32x4 a, const f32x4 b, s16x8* hi, s16x8* lo) {
#pragma unroll
  for (int j = 0; j < 4; ++j) {
    unsigned short h = bf16_rne(a[j]);
    (*hi)[j] = (short)h; (*lo)[j] = (short)bf16_rne(a[j] - bf16f(h));
  }
#pragma unroll
  for (int j = 0; j < 4; ++j) {
    unsigned short h = bf16_rne(b[j]);
    (*hi)[4 + j] = (short)h; (*lo)[4 + j] = (short)bf16_rne(b[j] - bf16f(h));
  }
}

// ---------------- Phase 1: split-bf16 MFMA logits (unchanged) ----------------
__global__ __launch_bounds__(128, 1)
void mfma_logits(const float* __restrict__ x, const float* __restrict__ w,
                 const float* __restrict__ bias, float* __restrict__ lg)
{
  __shared__ s16x8 Ah[2][64], Al[2][64], Bh[4][64], Bl[4][64];  // 12 KB

  const int t = threadIdx.x;
  const int wv = t >> 6, lane = t & 63;
  const int rowBase = blockIdx.x << 5;

  const int xr = t >> 2;
  const int xm = xr >> 4;
  const int xl = ((t & 3) << 4) | (xr & 15);
  const float* xbase = x + (size_t)(rowBase + xr) * DIM + ((t & 3) << 3);

  const int we = t >> 1;
  const int wn = we >> 4;
  const int kg0 = (t & 1) << 1;
  const int wl0 = (kg0 << 4) | (we & 15);
  const int wl1 = ((kg0 + 1) << 4) | (we & 15);
  const float* wbase = w + (size_t)we * DIM + ((t & 1) << 4);

  f32x4 acc[4];
#pragma unroll
  for (int n = 0; n < 4; ++n) acc[n] = (f32x4)(0.f);

  f32x4 cx0 = *(const f32x4*)(xbase);
  f32x4 cx1 = *(const f32x4*)(xbase + 4);
  f32x4 cw0 = *(const f32x4*)(wbase);
  f32x4 cw1 = *(const f32x4*)(wbase + 4);
  f32x4 cw2 = *(const f32x4*)(wbase + 8);
  f32x4 cw3 = *(const f32x4*)(wbase + 12);

#pragma unroll 1
  for (int kt = 0; kt < NKT; ++kt) {
    const int kn = ((kt + 1) & (NKT - 1)) * KSTEP;
    f32x4 nx0 = *(const f32x4*)(xbase + kn);
    f32x4 nx1 = *(const f32x4*)(xbase + kn + 4);
    f32x4 nw0 = *(const f32x4*)(wbase + kn);
    f32x4 nw1 = *(const f32x4*)(wbase + kn + 4);
    f32x4 nw2 = *(const f32x4*)(wbase + kn + 8);
    f32x4 nw3 = *(const f32x4*)(wbase + kn + 12);

    {
      s16x8 hi, lo;
      cvt8(cx0, cx1, &hi, &lo);
      Ah[xm][xl] = hi; Al[xm][xl] = lo;
      cvt8(cw0, cw1, &hi, &lo);
      Bh[wn][wl0] = hi; Bl[wn][wl0] = lo;
      cvt8(cw2, cw3, &hi, &lo);
      Bh[wn][wl1] = hi; Bl[wn][wl1] = lo;
    }
    asm volatile("s_waitcnt lgkmcnt(0)" ::: "memory");
    __builtin_amdgcn_s_barrier();

    {
      s16x8 a_h = Ah[wv][lane];
      s16x8 a_l = Al[wv][lane];
#pragma unroll
      for (int n = 0; n < 4; ++n) {
        s16x8 b_h = Bh[n][lane];
        s16x8 b_l = Bl[n][lane];
        acc[n] = __builtin_amdgcn_mfma_f32_16x16x32_bf16(a_l, b_h, acc[n], 0, 0, 0);
        acc[n] = __builtin_amdgcn_mfma_f32_16x16x32_bf16(a_h, b_l, acc[n], 0, 0, 0);
        acc[n] = __builtin_amdgcn_mfma_f32_16x16x32_bf16(a_h, b_h, acc[n], 0, 0, 0);
      }
    }
    __builtin_amdgcn_s_barrier();

    cx0 = nx0; cx1 = nx1; cw0 = nw0; cw1 = nw1; cw2 = nw2; cw3 = nw3;
  }

  const int orow = rowBase + (wv << 4) + ((lane >> 4) << 2);
  const int ocol = lane & 15;
#pragma unroll
  for (int n = 0; n < 4; ++n)
#pragma unroll
    for (int r = 0; r < 4; ++r)
      lg[(size_t)(orow + r) * NE + (n << 4) + ocol] = acc[n][r] + bias[(n << 4) + ocol];
}

// ---------------- Phase 2: finish — one wave per row ----------------
__global__ __launch_bounds__(256, 4)
void finish_kernel(float* __restrict__ gate, float* __restrict__ out_vals,
                   float* __restrict__ out_idx, int* __restrict__ flags, int maxf)
{
  const int t    = threadIdx.x;
  const int row  = blockIdx.x * 4 + (t >> 6);
  const int lane = t & 63;                 // lane == expert

  float l = gate[(size_t)row * NE + lane];

  // wave-reduce max (order-independent)
  float m = l;
#pragma unroll
  for (int d = 32; d >= 1; d >>= 1) m = fmaxf(m, __shfl_xor(m, d));
  float pe = expf(l - m);
  // tree sum (tolerance >> tree-vs-pairwise delta; ranking unaffected)
  float s = pe;
#pragma unroll
  for (int d = 32; d >= 1; d >>= 1) s = s + __shfl_xor(s, d);
  float p = pe / s;

  // top-9 by logits: 9 lexicographic tournament reductions
  // (val desc, idx asc) == serial first-max scan (strict >, lowest idx tie).
  float cur = l;
  float sval[9]; int sidx[9];
  unsigned long long used8 = 0;
#pragma unroll
  for (int k = 0; k < 9; ++k) {
    float v = cur; int i = lane;
#pragma unroll
    for (int d = 1; d < 64; d <<= 1) {
      float ov = __shfl_xor(v, d);
      int   oi = __shfl_xor(i, d);
      bool take = (ov > v) || (ov == v && oi < i);
      v = take ? ov : v;
      i = take ? oi : i;
    }
    sval[k] = v; sidx[k] = i;
    if (k < 8) {
      used8 |= 1ull << i;
      if (lane == i) cur = -INFINITY;
    }
  }

  // vals/idx: lane k (<8) writes entry k
  float myv = 0.f, myi = 0.f;
#pragma unroll
  for (int k = 0; k < 8; ++k) {
    float pv = __shfl(p, sidx[k]);
    if (lane == k) { myv = pv; myi = (float)sidx[k]; }
  }
  if (lane < 8) {
    out_vals[(size_t)row * 8 + lane] = myv;
    out_idx [(size_t)row * 8 + lane] = myi;
  }

  // dense gate (in-place over logits): coalesced lane store
  gate[(size_t)row * NE + lane] = ((used8 >> lane) & 1ull) ? p : 0.0f;

  // flag near-tie rows (wave-uniform branch)
  float ming = INFINITY;
#pragma unroll
  for (int k = 1; k < 9; ++k) ming = fminf(ming, sval[k - 1] - sval[k]);
  if (ming < MARGIN && maxf > 0) {
    unsigned long long cmask = __ballot(l >= sval[7] - MARGIN);
    int n = __popcll(cmask);
    if (n <= MAXCAND) {   // overflow: keep approx result (~1e-9 probability)
      int slot = 0;
      if (lane == 0) slot = atomicAdd(flags, 1);
      slot = __shfl(slot, 0);
      if (slot < maxf) {
        int* rec = flags + 4 + slot * 32;
        if (lane == 0) { rec[0] = row; rec[1] = n; }
        if ((cmask >> lane) & 1ull) {
          int pos = __popcll(cmask & ((1ull << lane) - 1ull));  // ascending e
          rec[2 + pos] = lane;
          ((float*)(rec + 14))[pos] = p;
        }
      }
    }
  }
}

// ---------------- Phase 3: np-exact fixup for flagged rows (unchanged) -------
__global__ __launch_bounds__(64, 1)
void exact_fix(const float* __restrict__ x, const float* __restrict__ w,
               const float* __restrict__ bias, const int* __restrict__ flags,
               int maxf, float* __restrict__ out_vals, float* __restrict__ out_idx,
               float* __restrict__ gate)
{
  __shared__ float xs_[DIM];                 // 8 KB
  __shared__ float wl_[MAXCAND * DIM];       // 96 KB
  __shared__ float exl[MAXCAND];

  int count = flags[0]; if (count > maxf) count = maxf;
  const int lane = threadIdx.x;

  for (int recI = blockIdx.x; recI < count; recI += (int)gridDim.x) {
    const int* rec = flags + 4 + recI * 32;
    const int row = rec[0], n = rec[1];

#pragma unroll
    for (int i = 0; i < 8; ++i)
      ld16_lds(x + (size_t)row * DIM + i * 256 + lane * 4, &xs_[i * 256 + lane * 4]);
    for (int c = 0; c < n; ++c)
#pragma unroll
      for (int i = 0; i < 8; ++i)
        ld16_lds(w + (size_t)rec[2 + c] * DIM + i * 256 + lane * 4,
                 &wl_[c * DIM + i * 256 + lane * 4]);
    asm volatile("s_waitcnt vmcnt(0)" ::: "memory");
    __builtin_amdgcn_s_barrier();

    // np-exact chain: lane = cand*4 + npLane j; reverse in-block, unfused
    const int c = lane >> 2, jj = lane & 3;
    const int cw = (c < n) ? c : 0;
    const float* wrow = &wl_[cw * DIM];
    float a = 0.f;
#pragma unroll 4
    for (int b = 0; b < 128; ++b) {
      const int k = (b << 4) + jj;
      a = a + xs_[k + 12] * wrow[k + 12];
      a = a + xs_[k + 8]  * wrow[k + 8];
      a = a + xs_[k + 4]  * wrow[k + 4];
      a = a + xs_[k]      * wrow[k];
    }
    // SSE3 hadd tree: (L0+L1)+(L2+L3)  (f32 add is commutative-exact)
    float o1 = __shfl_xor(a, 1);
    float s01 = a + o1;
    float o2 = __shfl_xor(s01, 2);
    float tot = (s01 + o2) + bias[rec[2 + cw]];
    if (jj == 0 && c < n) exl[c] = tot;
    __syncthreads();

    if (lane == 0) {
      unsigned used = 0;
      const float* cp = (const float*)(rec + 14);
      for (int k = 0; k < 8; ++k) {
        float best = -INFINITY; int bi = 0;
        for (int c2 = 0; c2 < n; ++c2) {
          bool ok = (((used >> c2) & 1u) == 0u) && (exl[c2] > best);
          best = ok ? exl[c2] : best;
          bi   = ok ? c2      : bi;
        }
        used |= 1u << bi;
        out_vals[(size_t)row * 8 + k] = cp[bi];
        out_idx [(size_t)row * 8 + k] = (float)rec[2 + bi];
      }
      for (int c2 = 0; c2 < n; ++c2)
        gate[(size_t)row * NE + rec[2 + c2]] = ((used >> c2) & 1u) ? cp[c2] : 0.f;
    }
    __syncthreads();
  }
}

extern "C" void kernel_launch(void* const* d_in, const int* in_sizes, int n_in,
                              void* d_out, int out_size, void* d_ws, size_t ws_size,
                              hipStream_t stream) {
  const float* x    = (const float*)d_in[0];
  const float* w    = (const float*)d_in[1];
  const float* bias = (const float*)d_in[2];
  float* out   = (float*)d_out;
  float* vals  = out;                       // 16384*8
  float* idx   = out + (size_t)NROWS * 8;   // 16384*8
  float* dense = out + (size_t)NROWS * 16;  // 16384*64 (P1 logit scratch)
  (void)in_sizes; (void)n_in; (void)out_size;

  int maxf = 0;
  if (ws_size >= 16 + 32 * 4) {
    size_t cap = (ws_size / 4 - 4) / 32;
    maxf = (int)(cap > 2048 ? 2048 : cap);
  }
  int* flags = (int*)d_ws;

  mfma_logits<<<dim3(NROWS / 32), dim3(128), 0, stream>>>(x, w, bias, dense);
  if (maxf > 0) hipMemsetAsync(d_ws, 0, 16, stream);
  finish_kernel<<<dim3(NROWS / 4), dim3(256), 0, stream>>>(dense, vals, idx, flags, maxf);
  if (maxf > 0)
    exact_fix<<<dim3(128), dim3(64), 0, stream>>>(x, w, bias, flags, maxf, vals, idx, dense);
}